// Round 1
// baseline (197.614 us; speedup 1.0000x reference)
//
#include <hip/hip_runtime.h>
#include <hip/hip_bf16.h>
#include <cstdint>

#define B_ 8
#define S_ 2048
#define D_ 1024
#define U_ 1024
#define M_ (B_ * S_)   // 16384 rows

typedef __bf16 bf16x8 __attribute__((ext_vector_type(8)));
typedef float  f32x4  __attribute__((ext_vector_type(4)));

__device__ __forceinline__ uint16_t f2bf(float f) {
  uint32_t u = __builtin_bit_cast(uint32_t, f);
  u += 0x7fffu + ((u >> 16) & 1u);   // RNE
  return (uint16_t)(u >> 16);
}

// async 16B global->LDS copy (lane-contiguous LDS destination)
__device__ __forceinline__ void async_copy16(const void* g, void* l) {
  typedef const __attribute__((address_space(1))) uint8_t* gp_t;
  typedef __attribute__((address_space(3))) uint8_t* lp_t;
  __builtin_amdgcn_global_load_lds((gp_t)(uintptr_t)g,
                                   (lp_t)(uint32_t)(uintptr_t)l, 16, 0, 0);
}

// ---------------- kernel 1: w [D][U] f32 -> w_t [U][D] bf16 (transpose+convert)
__global__ __launch_bounds__(256) void k_conv_w(const float* __restrict__ w,
                                                uint16_t* __restrict__ wt) {
  __shared__ float tile[32][33];
  const int t = threadIdx.x;
  const int tx = t & 31, ty = t >> 5;       // ty 0..7
  const int c0 = blockIdx.x * 32;           // U
  const int r0 = blockIdx.y * 32;           // D
#pragma unroll
  for (int i = 0; i < 4; i++) {
    int r = ty + i * 8;
    tile[r][tx] = w[(size_t)(r0 + r) * U_ + c0 + tx];
  }
  __syncthreads();
#pragma unroll
  for (int i = 0; i < 4; i++) {
    int r = ty + i * 8;
    wt[(size_t)(c0 + r) * D_ + r0 + tx] = f2bf(tile[tx][r]);
  }
}

// ---------------- kernel 2: attention softmax (fp32) + x -> bf16 conversion
__global__ __launch_bounds__(256) void k_attn_convx(
    const float* __restrict__ x, const float* __restrict__ w_att,
    const float* __restrict__ b_att, uint16_t* __restrict__ x_bf,
    float* __restrict__ attn) {
  const int row = blockIdx.x;        // 0..M_-1
  const int t = threadIdx.x;         // 256 threads, 4 floats each
  const float4 xv = reinterpret_cast<const float4*>(x + (size_t)row * D_)[t];
  float xe0 = xv.x, xe1 = xv.y, xe2 = xv.z, xe3 = xv.w;

  const float4* wa4 = reinterpret_cast<const float4*>(w_att);
  float p0 = 0.f, p1 = 0.f, p2 = 0.f, p3 = 0.f;
  float xs[4] = {xe0, xe1, xe2, xe3};
#pragma unroll
  for (int e = 0; e < 4; e++) {
    float4 wv = wa4[t * 4 + e];
    p0 = fmaf(xs[e], wv.x, p0);
    p1 = fmaf(xs[e], wv.y, p1);
    p2 = fmaf(xs[e], wv.z, p2);
    p3 = fmaf(xs[e], wv.w, p3);
  }

  // store bf16 row
  ushort4 hb;
  hb.x = f2bf(xe0); hb.y = f2bf(xe1); hb.z = f2bf(xe2); hb.w = f2bf(xe3);
  reinterpret_cast<ushort4*>(x_bf + (size_t)row * D_)[t] = hb;

  // wave64 reduce then cross-wave via LDS
#pragma unroll
  for (int off = 32; off > 0; off >>= 1) {
    p0 += __shfl_down(p0, off);
    p1 += __shfl_down(p1, off);
    p2 += __shfl_down(p2, off);
    p3 += __shfl_down(p3, off);
  }
  __shared__ float red[4][4];
  const int lane = t & 63, wid = t >> 6;
  if (lane == 0) { red[wid][0] = p0; red[wid][1] = p1; red[wid][2] = p2; red[wid][3] = p3; }
  __syncthreads();
  if (t == 0) {
    float l0 = red[0][0] + red[1][0] + red[2][0] + red[3][0] + b_att[0];
    float l1 = red[0][1] + red[1][1] + red[2][1] + red[3][1] + b_att[1];
    float l2 = red[0][2] + red[1][2] + red[2][2] + red[3][2] + b_att[2];
    float l3 = red[0][3] + red[1][3] + red[2][3] + red[3][3] + b_att[3];
    float mx = fmaxf(fmaxf(l0, l1), fmaxf(l2, l3));
    float e0 = __expf(l0 - mx), e1 = __expf(l1 - mx);
    float e2 = __expf(l2 - mx), e3 = __expf(l3 - mx);
    float inv = 1.f / (e0 + e1 + e2 + e3);
    reinterpret_cast<float4*>(attn)[row] = make_float4(e0 * inv, e1 * inv, e2 * inv, e3 * inv);
  }
}

// ---------------- kernel 3: bf16 MFMA GEMM (x_bf @ w_t^T) + fused activation epilogue
#define BM 128
#define BN 128
#define BK 64

__global__ __launch_bounds__(256) void k_gemm_ep(
    const uint16_t* __restrict__ xbf, const uint16_t* __restrict__ wt,
    const float* __restrict__ bias, const float* __restrict__ wf,
    const float* __restrict__ bfb, const float* __restrict__ attn,
    float* __restrict__ out) {
  __shared__ uint16_t As[BM * BK];   // [row m][k], 8-elem chunks XOR-swizzled by row&7
  __shared__ uint16_t Bs[BN * BK];   // [col n][k], same swizzle

  const int t = threadIdx.x;
  const int wave = t >> 6, lane = t & 63;
  const int l16 = lane & 15, quad = lane >> 4;
  const int wm = wave >> 1, wn = wave & 1;
  const int m0 = blockIdx.y * BM;
  const int n0 = blockIdx.x * BN;

  const uint16_t* aBase = xbf + (size_t)m0 * D_;
  const uint16_t* bBase = wt + (size_t)n0 * D_;

  f32x4 acc[4][4] = {};

  for (int k0 = 0; k0 < D_; k0 += BK) {
#pragma unroll
    for (int it = 0; it < 4; it++) {
      int c = t + it * 256;          // chunk id: per-wave lane-contiguous
      int r = c >> 3;                // tile row (m for A, n for B)
      int cs = c & 7;                // swizzled chunk slot
      int gc = cs ^ (r & 7);         // global chunk
      async_copy16(aBase + (size_t)r * D_ + k0 + gc * 8, (uint8_t*)As + c * 16);
      async_copy16(bBase + (size_t)r * D_ + k0 + gc * 8, (uint8_t*)Bs + c * 16);
    }
    __syncthreads();                 // compiler emits vmcnt(0) drain before barrier

#pragma unroll
    for (int ks = 0; ks < 2; ks++) {
      const int kcb = ks * 4;        // chunk base within row (kk/8)
      bf16x8 af[4], bfr[4];
#pragma unroll
      for (int i = 0; i < 4; i++) {
        int r = wm * 64 + i * 16 + l16;
        int cs = (kcb + quad) ^ (r & 7);
        af[i] = *reinterpret_cast<const bf16x8*>(&As[r * BK + cs * 8]);
      }
#pragma unroll
      for (int j = 0; j < 4; j++) {
        int n = wn * 64 + j * 16 + l16;
        int cs = (kcb + quad) ^ (n & 7);
        bfr[j] = *reinterpret_cast<const bf16x8*>(&Bs[n * BK + cs * 8]);
      }
#pragma unroll
      for (int i = 0; i < 4; i++)
#pragma unroll
        for (int j = 0; j < 4; j++)
          acc[i][j] = __builtin_amdgcn_mfma_f32_16x16x32_bf16(af[i], bfr[j], acc[i][j], 0, 0, 0);
    }
    __syncthreads();
  }

  // ---- fused epilogue: 4 activations + attention-weighted reduce
  float bu[4];
  float4 wf4[4], bf4[4];
#pragma unroll
  for (int j = 0; j < 4; j++) {
    int u = n0 + wn * 64 + j * 16 + l16;
    bu[j] = bias[u];
    wf4[j] = reinterpret_cast<const float4*>(wf)[u];
    bf4[j] = reinterpret_cast<const float4*>(bfb)[u];
  }
#pragma unroll
  for (int i = 0; i < 4; i++) {
#pragma unroll
    for (int r = 0; r < 4; r++) {
      int mg = m0 + wm * 64 + i * 16 + quad * 4 + r;   // C/D: row = quad*4+reg
      float4 at = reinterpret_cast<const float4*>(attn)[mg];
      float* orow = out + (size_t)mg * U_;
#pragma unroll
      for (int j = 0; j < 4; j++) {
        int u = n0 + wn * 64 + j * 16 + l16;            // C/D: col = lane&15
        float wsv = acc[i][j][r] + bu[j];
        float wa0 = fmaf(wsv, wf4[j].x, bf4[j].x);
        float wa1 = fmaf(wsv, wf4[j].y, bf4[j].y);
        float wa2 = fmaf(wsv, wf4[j].z, bf4[j].z);
        float wa3 = fmaf(wsv, wf4[j].w, bf4[j].w);
        float a_relu = fmaxf(wa0, 0.f);
        float a_sig = 1.f / (1.f + __expf(-wa1));
        float ax = fabsf(wa2);
        float et = __expf(-2.f * ax);
        float a_tanh = copysignf((1.f - et) / (1.f + et), wa2);
        float a_gelu = 0.5f * wa3 * (1.f + erff(wa3 * 0.70710678118654752f));
        orow[u] = at.x * a_relu + at.y * a_sig + at.z * a_tanh + at.w * a_gelu;
      }
    }
  }
}

extern "C" void kernel_launch(void* const* d_in, const int* in_sizes, int n_in,
                              void* d_out, int out_size, void* d_ws, size_t ws_size,
                              hipStream_t stream) {
  const float* x     = (const float*)d_in[0];
  const float* w     = (const float*)d_in[1];
  const float* b     = (const float*)d_in[2];
  const float* wf    = (const float*)d_in[3];
  const float* bfb   = (const float*)d_in[4];
  const float* w_att = (const float*)d_in[5];
  const float* b_att = (const float*)d_in[6];
  float* out = (float*)d_out;

  char* ws = (char*)d_ws;
  uint16_t* x_bf = (uint16_t*)ws;                          // 32 MiB
  uint16_t* w_t  = (uint16_t*)(ws + ((size_t)32 << 20));   // 2 MiB
  float*    attn = (float*)(ws + ((size_t)34 << 20));      // 256 KiB

  k_conv_w<<<dim3(U_ / 32, D_ / 32), 256, 0, stream>>>(w, w_t);
  k_attn_convx<<<dim3(M_), 256, 0, stream>>>(x, w_att, b_att, x_bf, attn);
  k_gemm_ep<<<dim3(U_ / BN, M_ / BM), 256, 0, stream>>>(x_bf, w_t, b, wf, bfb, attn, out);
}

// Round 2
// 178.787 us; speedup vs baseline: 1.1053x; 1.1053x over previous
//
#include <hip/hip_runtime.h>
#include <hip/hip_bf16.h>
#include <cstdint>

#define B_ 8
#define S_ 2048
#define D_ 1024
#define U_ 1024
#define M_ (B_ * S_)   // 16384 rows

typedef __bf16 bf16x8 __attribute__((ext_vector_type(8)));
typedef float  f32x4  __attribute__((ext_vector_type(4)));

__device__ __forceinline__ uint16_t f2bf(float f) {
  uint32_t u = __builtin_bit_cast(uint32_t, f);
  u += 0x7fffu + ((u >> 16) & 1u);   // RNE
  return (uint16_t)(u >> 16);
}

// async 16B global->LDS copy (lane-contiguous LDS destination)
__device__ __forceinline__ void async_copy16(const void* g, void* l) {
  typedef const __attribute__((address_space(1))) uint8_t* gp_t;
  typedef __attribute__((address_space(3))) uint8_t* lp_t;
  __builtin_amdgcn_global_load_lds((gp_t)(uintptr_t)g,
                                   (lp_t)(uint32_t)(uintptr_t)l, 16, 0, 0);
}

// ---------------- kernel 1 (fused prep):
//   blocks [0, M_/4):      wave-per-row: x -> x_bf (bf16) + attn softmax (no barriers)
//   blocks [M_/4, +1024):  w [D][U] f32 -> wt [U][D] bf16 (LDS tile transpose)
__global__ __launch_bounds__(256) void k_prep(
    const float* __restrict__ x, const float* __restrict__ w_att,
    const float* __restrict__ b_att, const float* __restrict__ w,
    uint16_t* __restrict__ x_bf, float* __restrict__ attn,
    uint16_t* __restrict__ wt) {
  __shared__ float tile[32][33];     // used only by transpose blocks
  const int bid = blockIdx.x;
  if (bid < M_ / 4) {
    const int wave = threadIdx.x >> 6, lane = threadIdx.x & 63;
    const int row = bid * 4 + wave;
    const float4* xr = reinterpret_cast<const float4*>(x + (size_t)row * D_);
    const float4* wa4 = reinterpret_cast<const float4*>(w_att);
    float4 v[4];
#pragma unroll
    for (int i = 0; i < 4; i++) v[i] = xr[lane + 64 * i];   // 16 B/lane coalesced
    float4 p = {0.f, 0.f, 0.f, 0.f};
#pragma unroll
    for (int i = 0; i < 4; i++) {
      const int base = 4 * (lane + 64 * i);
      const float xe[4] = {v[i].x, v[i].y, v[i].z, v[i].w};
#pragma unroll
      for (int c = 0; c < 4; c++) {
        float4 wv = wa4[base + c];   // 16 KiB table, L1-hot
        p.x = fmaf(xe[c], wv.x, p.x);
        p.y = fmaf(xe[c], wv.y, p.y);
        p.z = fmaf(xe[c], wv.z, p.z);
        p.w = fmaf(xe[c], wv.w, p.w);
      }
      ushort4 hb;
      hb.x = f2bf(v[i].x); hb.y = f2bf(v[i].y);
      hb.z = f2bf(v[i].z); hb.w = f2bf(v[i].w);
      reinterpret_cast<ushort4*>(x_bf + (size_t)row * D_)[lane + 64 * i] = hb;
    }
    // in-wave butterfly reduce (no LDS, no barrier)
#pragma unroll
    for (int off = 32; off > 0; off >>= 1) {
      p.x += __shfl_xor(p.x, off);
      p.y += __shfl_xor(p.y, off);
      p.z += __shfl_xor(p.z, off);
      p.w += __shfl_xor(p.w, off);
    }
    if (lane == 0) {
      float l0 = p.x + b_att[0], l1 = p.y + b_att[1];
      float l2 = p.z + b_att[2], l3 = p.w + b_att[3];
      float mx = fmaxf(fmaxf(l0, l1), fmaxf(l2, l3));
      float e0 = __expf(l0 - mx), e1 = __expf(l1 - mx);
      float e2 = __expf(l2 - mx), e3 = __expf(l3 - mx);
      float inv = __builtin_amdgcn_rcpf(e0 + e1 + e2 + e3);
      reinterpret_cast<float4*>(attn)[row] =
          make_float4(e0 * inv, e1 * inv, e2 * inv, e3 * inv);
    }
  } else {
    const int wid = bid - M_ / 4;
    const int t = threadIdx.x;
    const int tx = t & 31, ty = t >> 5;
    const int c0 = (wid & 31) * 32;   // U
    const int r0 = (wid >> 5) * 32;   // D
#pragma unroll
    for (int i = 0; i < 4; i++) {
      int r = ty + i * 8;
      tile[r][tx] = w[(size_t)(r0 + r) * U_ + c0 + tx];
    }
    __syncthreads();
#pragma unroll
    for (int i = 0; i < 4; i++) {
      int r = ty + i * 8;
      wt[(size_t)(c0 + r) * D_ + r0 + tx] = f2bf(tile[tx][r]);
    }
  }
}

// ---------------- kernel 2: bf16 MFMA GEMM (x_bf @ w_t^T) + fused fast-math epilogue
#define BM 128
#define BN 128
#define BK 64

__global__ __launch_bounds__(256, 4) void k_gemm_ep(
    const uint16_t* __restrict__ xbf, const uint16_t* __restrict__ wt,
    const float* __restrict__ bias, const float* __restrict__ wf,
    const float* __restrict__ bfb, const float* __restrict__ attn,
    float* __restrict__ out) {
  __shared__ uint16_t As[BM * BK];   // [row m][k], 8-elem chunks XOR-swizzled by row&7
  __shared__ uint16_t Bs[BN * BK];   // [col n][k], same swizzle

  const int t = threadIdx.x;
  const int wave = t >> 6, lane = t & 63;
  const int l16 = lane & 15, quad = lane >> 4;
  const int wm = wave >> 1, wn = wave & 1;
  const int m0 = blockIdx.y * BM;
  const int n0 = blockIdx.x * BN;

  const uint16_t* aBase = xbf + (size_t)m0 * D_;
  const uint16_t* bBase = wt + (size_t)n0 * D_;

  f32x4 acc[4][4] = {};

  for (int k0 = 0; k0 < D_; k0 += BK) {
#pragma unroll
    for (int it = 0; it < 4; it++) {
      int c = t + it * 256;          // chunk id: per-wave lane-contiguous
      int r = c >> 3;                // tile row (m for A, n for B)
      int cs = c & 7;                // swizzled chunk slot
      int gc = cs ^ (r & 7);         // global chunk
      async_copy16(aBase + (size_t)r * D_ + k0 + gc * 8, (uint8_t*)As + c * 16);
      async_copy16(bBase + (size_t)r * D_ + k0 + gc * 8, (uint8_t*)Bs + c * 16);
    }
    __syncthreads();

#pragma unroll
    for (int ks = 0; ks < 2; ks++) {
      const int kcb = ks * 4;        // chunk base within row (kk/8)
      bf16x8 af[4], bfr[4];
#pragma unroll
      for (int i = 0; i < 4; i++) {
        int r = wm * 64 + i * 16 + l16;
        int cs = (kcb + quad) ^ (r & 7);
        af[i] = *reinterpret_cast<const bf16x8*>(&As[r * BK + cs * 8]);
      }
#pragma unroll
      for (int j = 0; j < 4; j++) {
        int n = wn * 64 + j * 16 + l16;
        int cs = (kcb + quad) ^ (n & 7);
        bfr[j] = *reinterpret_cast<const bf16x8*>(&Bs[n * BK + cs * 8]);
      }
#pragma unroll
      for (int i = 0; i < 4; i++)
#pragma unroll
        for (int j = 0; j < 4; j++)
          acc[i][j] = __builtin_amdgcn_mfma_f32_16x16x32_bf16(af[i], bfr[j], acc[i][j], 0, 0, 0);
    }
    __syncthreads();
  }

  // ---- fused epilogue: 4 activations (fast-math) + attention-weighted reduce
  float bu[4];
  float4 wf4[4], bf4[4];
#pragma unroll
  for (int j = 0; j < 4; j++) {
    int u = n0 + wn * 64 + j * 16 + l16;
    bu[j] = bias[u];
    wf4[j] = reinterpret_cast<const float4*>(wf)[u];
    bf4[j] = reinterpret_cast<const float4*>(bfb)[u];
  }
#pragma unroll
  for (int i = 0; i < 4; i++) {
#pragma unroll
    for (int r = 0; r < 4; r++) {
      int mg = m0 + wm * 64 + i * 16 + quad * 4 + r;   // C/D: row = quad*4+reg
      float4 at = reinterpret_cast<const float4*>(attn)[mg];
      float* orow = out + (size_t)mg * U_;
#pragma unroll
      for (int j = 0; j < 4; j++) {
        int u = n0 + wn * 64 + j * 16 + l16;            // C/D: col = lane&15
        float wsv = acc[i][j][r] + bu[j];
        float wa0 = fmaf(wsv, wf4[j].x, bf4[j].x);
        float wa1 = fmaf(wsv, wf4[j].y, bf4[j].y);
        float wa2 = fmaf(wsv, wf4[j].z, bf4[j].z);
        float wa3 = fmaf(wsv, wf4[j].w, bf4[j].w);
        // relu
        float a_relu = fmaxf(wa0, 0.f);
        // sigmoid(x) = rcp(1 + 2^(-log2e*x))
        float a_sig = __builtin_amdgcn_rcpf(
            1.f + __builtin_amdgcn_exp2f(-1.4426950409f * wa1));
        // tanh(x) = 2*sigmoid(2x) - 1
        float a_tanh = fmaf(2.f, __builtin_amdgcn_rcpf(
            1.f + __builtin_amdgcn_exp2f(-2.8853900818f * wa2)), -1.f);
        // gelu(x) ~= x * sigmoid(2*0.7978845608*(x + 0.044715 x^3))
        float y = wa3 * fmaf(0.044715f, wa3 * wa3, 1.f);
        float a_gelu = wa3 * __builtin_amdgcn_rcpf(
            1.f + __builtin_amdgcn_exp2f(-2.302207929f * y));
        orow[u] = at.x * a_relu + at.y * a_sig + at.z * a_tanh + at.w * a_gelu;
      }
    }
  }
}

extern "C" void kernel_launch(void* const* d_in, const int* in_sizes, int n_in,
                              void* d_out, int out_size, void* d_ws, size_t ws_size,
                              hipStream_t stream) {
  const float* x     = (const float*)d_in[0];
  const float* w     = (const float*)d_in[1];
  const float* b     = (const float*)d_in[2];
  const float* wf    = (const float*)d_in[3];
  const float* bfb   = (const float*)d_in[4];
  const float* w_att = (const float*)d_in[5];
  const float* b_att = (const float*)d_in[6];
  float* out = (float*)d_out;

  char* ws = (char*)d_ws;
  uint16_t* x_bf = (uint16_t*)ws;                          // 32 MiB
  uint16_t* w_t  = (uint16_t*)(ws + ((size_t)32 << 20));   // 2 MiB
  float*    attn = (float*)(ws + ((size_t)34 << 20));      // 256 KiB

  k_prep<<<dim3(M_ / 4 + 1024), 256, 0, stream>>>(x, w_att, b_att, w, x_bf, attn, w_t);
  k_gemm_ep<<<dim3(U_ / BN, M_ / BM), 256, 0, stream>>>(x_bf, w_t, b, wf, bfb, attn, out);
}